// Round 1
// baseline (548.340 us; speedup 1.0000x reference)
//
#include <hip/hip_runtime.h>

#define N_NODES 50000
#define N_EDGES 600000
#define D_IN 128
#define D_MID 128
#define D_ATTR 32
#define D_OUT 128
#define D_EMB 256
#define D_H 768
#define K_TOP 16
#define D_CAT (D_OUT + D_ATTR)   // 160

// ---------------------------------------------------------------- init
__global__ void k_init(float* deg, int* counts, float* colsum, float* q) {
    int i = blockIdx.x * blockDim.x + threadIdx.x;
    if (i < N_NODES) { deg[i] = 1.0f; counts[i] = 0; }
    if (i < D_CAT)   { colsum[i] = 0.0f; q[i] = 0.0f; }
}

// ---------------------------------------------------------------- degree + histogram
__global__ void k_deg(const int* __restrict__ dst, const float* __restrict__ w,
                      float* deg, int* counts) {
    int e = blockIdx.x * blockDim.x + threadIdx.x;
    if (e < N_EDGES) {
        int d = dst[e];
        atomicAdd(&deg[d], w[e]);
        atomicAdd(&counts[d], 1);
    }
}

__global__ void k_dinv(float* deg) {
    int i = blockIdx.x * blockDim.x + threadIdx.x;
    if (i < N_NODES) deg[i] = rsqrtf(deg[i]);   // deg >= 1 always (self loop)
}

// ---------------------------------------------------------------- exclusive scan (single block)
__global__ void k_scan(const int* __restrict__ counts, int* __restrict__ row_ptr,
                       int* __restrict__ cursor) {
    __shared__ int sm[1024];
    __shared__ int carry_s;
    int tid = threadIdx.x;
    if (tid == 0) { carry_s = 0; row_ptr[0] = 0; }
    __syncthreads();
    for (int base = 0; base < N_NODES; base += 1024) {
        int i = base + tid;
        int v = (i < N_NODES) ? counts[i] : 0;
        sm[tid] = v;
        __syncthreads();
        for (int off = 1; off < 1024; off <<= 1) {
            int t = (tid >= off) ? sm[tid - off] : 0;
            __syncthreads();
            sm[tid] += t;
            __syncthreads();
        }
        int carry = carry_s;
        if (i < N_NODES) {
            row_ptr[i + 1] = carry + sm[tid];
            cursor[i] = carry + sm[tid] - v;       // exclusive prefix = row_ptr[i]
        }
        __syncthreads();
        if (tid == 1023) carry_s = carry + sm[1023];
        __syncthreads();
    }
}

// ---------------------------------------------------------------- CSR fill
__global__ void k_fill(const int* __restrict__ src, const int* __restrict__ dst,
                       const float* __restrict__ w, const float* __restrict__ dinv,
                       int* __restrict__ cursor, int* __restrict__ col,
                       float* __restrict__ nrm) {
    int e = blockIdx.x * blockDim.x + threadIdx.x;
    if (e < N_EDGES) {
        int s = src[e], d = dst[e];
        int pos = atomicAdd(&cursor[d], 1);
        col[pos] = s;
        nrm[pos] = dinv[s] * w[e] * dinv[d];
    }
}

// ---------------------------------------------------------------- GEMM: out[N,128] = [in1|in2] @ W
#define BM 64
#define KT 32
__global__ __launch_bounds__(256) void k_gemm(
    const float* __restrict__ in1, int d1,
    const float* __restrict__ in2, int d2,
    const float* __restrict__ W,      // [(d1+d2) x 128]
    float* __restrict__ out)          // [N x 128]
{
    __shared__ float xs[BM][KT + 1];
    __shared__ float ws[KT][128];
    int tid = threadIdx.x;
    int cx = tid & 15;        // col group: cols cx*8 .. cx*8+7
    int ry = tid >> 4;        // row group: rows ry*4 .. ry*4+3
    int row0 = blockIdx.x * BM;
    float acc[4][8];
#pragma unroll
    for (int a = 0; a < 4; a++)
#pragma unroll
        for (int b = 0; b < 8; b++) acc[a][b] = 0.0f;
    int KD = d1 + d2;
    for (int kt = 0; kt < KD; kt += KT) {
        for (int idx = tid; idx < BM * KT; idx += 256) {
            int rr = idx >> 5;        // KT == 32
            int kk = idx & 31;
            int r = row0 + rr, kg = kt + kk;
            float v = 0.0f;
            if (r < N_NODES)
                v = (kg < d1) ? in1[r * d1 + kg] : in2[r * d2 + (kg - d1)];
            xs[rr][kk] = v;
        }
        for (int idx = tid; idx < KT * 128; idx += 256) {
            int kk = idx >> 7;
            int c = idx & 127;
            ws[kk][c] = W[(kt + kk) * 128 + c];
        }
        __syncthreads();
#pragma unroll
        for (int kk = 0; kk < KT; ++kk) {
            float x0 = xs[ry * 4 + 0][kk];
            float x1 = xs[ry * 4 + 1][kk];
            float x2 = xs[ry * 4 + 2][kk];
            float x3 = xs[ry * 4 + 3][kk];
            float wv[8];
#pragma unroll
            for (int j = 0; j < 8; j++) wv[j] = ws[kk][cx * 8 + j];
#pragma unroll
            for (int j = 0; j < 8; j++) {
                acc[0][j] += x0 * wv[j];
                acc[1][j] += x1 * wv[j];
                acc[2][j] += x2 * wv[j];
                acc[3][j] += x3 * wv[j];
            }
        }
        __syncthreads();
    }
    for (int rr = 0; rr < 4; ++rr) {
        int r = row0 + ry * 4 + rr;
        if (r < N_NODES) {
            float4 v0 = make_float4(acc[rr][0], acc[rr][1], acc[rr][2], acc[rr][3]);
            float4 v1 = make_float4(acc[rr][4], acc[rr][5], acc[rr][6], acc[rr][7]);
            float4* o = (float4*)(out + r * 128 + cx * 8);
            o[0] = v0;
            o[1] = v1;
        }
    }
}

// ---------------------------------------------------------------- aggregation (CSR gather)
// 32 lanes per node, float4 per lane. out = sum_{e in row} nrm*t[col] + dinv^2*t[node] + bias
__global__ __launch_bounds__(256) void k_agg(
    const float* __restrict__ t, const float* __restrict__ dinv,
    const int* __restrict__ row_ptr, const int* __restrict__ col,
    const float* __restrict__ nrm, const float* __restrict__ bias,
    float* __restrict__ out, int relu_flag)
{
    int lane = threadIdx.x & 31;
    int node = blockIdx.x * 8 + (threadIdx.x >> 5);
    if (node >= N_NODES) return;
    const float4* t4 = (const float4*)t;
    float di = dinv[node];
    float sw = di * di;
    float4 v = t4[node * 32 + lane];
    float4 acc;
    acc.x = v.x * sw; acc.y = v.y * sw; acc.z = v.z * sw; acc.w = v.w * sw;
    int e0 = row_ptr[node], e1 = row_ptr[node + 1];
    for (int e = e0; e < e1; ++e) {
        int s = col[e];
        float wn = nrm[e];
        float4 u = t4[s * 32 + lane];
        acc.x += wn * u.x; acc.y += wn * u.y; acc.z += wn * u.z; acc.w += wn * u.w;
    }
    const float4* b4 = (const float4*)bias;
    float4 bb = b4[lane];
    acc.x += bb.x; acc.y += bb.y; acc.z += bb.z; acc.w += bb.w;
    if (relu_flag) {
        acc.x = fmaxf(acc.x, 0.0f); acc.y = fmaxf(acc.y, 0.0f);
        acc.z = fmaxf(acc.z, 0.0f); acc.w = fmaxf(acc.w, 0.0f);
    }
    ((float4*)out)[node * 32 + lane] = acc;
}

// ---------------------------------------------------------------- q = hidden_state @ Wattn  [160]
__global__ void k_q(const float* __restrict__ hs, const float* __restrict__ Wattn,
                    float* __restrict__ q) {
    int j = threadIdx.x;
    if (j >= D_CAT) return;
    int k0 = blockIdx.x * (D_H / 8);       // grid 8
    float acc = 0.0f;
    for (int k = k0; k < k0 + D_H / 8; k++) acc += hs[k] * Wattn[k * D_CAT + j];
    atomicAdd(&q[j], acc);
}

// ---------------------------------------------------------------- scores = [h2|attr] . q
__global__ __launch_bounds__(256) void k_scores(
    const float* __restrict__ h2, const float* __restrict__ attr,
    const float* __restrict__ q, float* __restrict__ scores)
{
    int lane = threadIdx.x & 31;
    int node = blockIdx.x * 8 + (threadIdx.x >> 5);
    if (node >= N_NODES) return;
    const float4* h4 = (const float4*)h2;
    const float4* q4 = (const float4*)q;
    float4 a = h4[node * 32 + lane];
    float4 qq = q4[lane];
    float s = a.x * qq.x + a.y * qq.y + a.z * qq.z + a.w * qq.w;
    if (lane < 8) {
        const float4* at4 = (const float4*)attr;
        float4 b = at4[node * 8 + lane];
        float4 q2 = q4[32 + lane];
        s += b.x * q2.x + b.y * q2.y + b.z * q2.z + b.w * q2.w;
    }
    for (int off = 16; off; off >>= 1) s += __shfl_xor(s, off, 32);
    if (lane == 0) scores[node] = s;
}

// ---------------------------------------------------------------- column sums for mean pool
__global__ void k_colsum(const float* __restrict__ h2, const float* __restrict__ attr,
                         float* __restrict__ colsum) {
    int j = threadIdx.x;
    int per = (N_NODES + gridDim.x - 1) / gridDim.x;
    int r0 = blockIdx.x * per;
    int r1 = min(N_NODES, r0 + per);
    float acc = 0.0f;
    if (j < D_OUT) {
        for (int i = r0; i < r1; i++) acc += h2[i * D_OUT + j];
        atomicAdd(&colsum[j], acc);
    } else if (j < D_CAT) {
        int jj = j - D_OUT;
        for (int i = r0; i < r1; i++) acc += attr[i * D_ATTR + jj];
        atomicAdd(&colsum[j], acc);
    }
}

// ---------------------------------------------------------------- top-k stage 1: per-chunk top-16
#define N_CHUNKBLKS 196
__global__ __launch_bounds__(256) void k_top1(const float* __restrict__ scores,
                                              float* __restrict__ cand_s,
                                              int* __restrict__ cand_i) {
    __shared__ float ss[256];
    __shared__ int si[256];
    __shared__ float rs[256];
    __shared__ int ri[256];
    int tid = threadIdx.x;
    int i = blockIdx.x * 256 + tid;
    ss[tid] = (i < N_NODES) ? scores[i] : -INFINITY;
    si[tid] = i;
    __syncthreads();
    for (int it = 0; it < K_TOP; ++it) {
        rs[tid] = ss[tid]; ri[tid] = si[tid];
        __syncthreads();
        for (int off = 128; off; off >>= 1) {
            if (tid < off) {
                float s2 = rs[tid + off]; int i2 = ri[tid + off];
                if (s2 > rs[tid] || (s2 == rs[tid] && i2 < ri[tid])) { rs[tid] = s2; ri[tid] = i2; }
            }
            __syncthreads();
        }
        if (tid == 0) {
            cand_s[blockIdx.x * K_TOP + it] = rs[0];
            cand_i[blockIdx.x * K_TOP + it] = ri[0];
        }
        __syncthreads();
        if (si[tid] == ri[0]) ss[tid] = -INFINITY;
        __syncthreads();
    }
}

// ---------------------------------------------------------------- stage 2 + emb + gather
#define N_CAND (N_CHUNKBLKS * K_TOP)   // 3136
__global__ __launch_bounds__(256) void k_final(
    const float* __restrict__ cand_s, const int* __restrict__ cand_i,
    const float* __restrict__ h2, const float* __restrict__ attr,
    const float* __restrict__ colsum, const float* __restrict__ Wmap,
    const float* __restrict__ bmap, float* __restrict__ out)
{
    __shared__ float ss[4096];
    __shared__ int si[4096];
    __shared__ float rs[256];
    __shared__ int ri[256];
    __shared__ int topidx[K_TOP];
    int tid = threadIdx.x;
    for (int i = tid; i < 4096; i += 256) {
        ss[i] = (i < N_CAND) ? cand_s[i] : -INFINITY;
        si[i] = (i < N_CAND) ? cand_i[i] : 0x7fffffff;
    }
    __syncthreads();
    for (int it = 0; it < K_TOP; ++it) {
        float bs = -INFINITY; int bi = 0x7fffffff;
        for (int i = tid; i < 4096; i += 256) {
            float s = ss[i]; int ii = si[i];
            if (s > bs || (s == bs && ii < bi)) { bs = s; bi = ii; }
        }
        rs[tid] = bs; ri[tid] = bi;
        __syncthreads();
        for (int off = 128; off; off >>= 1) {
            if (tid < off) {
                float s2 = rs[tid + off]; int i2 = ri[tid + off];
                if (s2 > rs[tid] || (s2 == rs[tid] && i2 < ri[tid])) { rs[tid] = s2; ri[tid] = i2; }
            }
            __syncthreads();
        }
        if (tid == 0) topidx[it] = ri[0];
        __syncthreads();
        for (int i = tid; i < 4096; i += 256)
            if (si[i] == ri[0]) ss[i] = -INFINITY;
        __syncthreads();
    }
    // emb = (colsum / N) @ Wmap + bmap  -> out[0:256]
    {
        float acc = 0.0f;
        for (int k = 0; k < D_CAT; k++) acc += colsum[k] * Wmap[k * D_EMB + tid];
        out[tid] = acc * (1.0f / N_NODES) + bmap[tid];
    }
    __syncthreads();
    // chose_nodes gather -> out[256 : 256 + 16*160]
    for (int idx = tid; idx < K_TOP * D_CAT; idx += 256) {
        int kk = idx / D_CAT;
        int d = idx % D_CAT;
        int node = topidx[kk];
        out[D_EMB + idx] = (d < D_OUT) ? h2[node * D_OUT + d]
                                       : attr[node * D_ATTR + (d - D_OUT)];
    }
}

// ================================================================ host
extern "C" void kernel_launch(void* const* d_in, const int* in_sizes, int n_in,
                              void* d_out, int out_size, void* d_ws, size_t ws_size,
                              hipStream_t stream) {
    const float* x      = (const float*)d_in[0];
    const float* attr   = (const float*)d_in[1];
    const float* ew     = (const float*)d_in[2];
    const float* hs     = (const float*)d_in[3];
    const int*   ei     = (const int*)d_in[4];      // [2,E] int32: row0=src, row1=dst
    const float* W1     = (const float*)d_in[5];
    const float* b1     = (const float*)d_in[6];
    const float* W2     = (const float*)d_in[7];
    const float* b2     = (const float*)d_in[8];
    const float* Wmap   = (const float*)d_in[9];
    const float* bmap   = (const float*)d_in[10];
    const float* Wattn  = (const float*)d_in[11];
    float* out = (float*)d_out;
    const int* e_src = ei;
    const int* e_dst = ei + N_EDGES;

    size_t off = 0;
    auto alloc = [&](size_t bytes) {
        void* p = (char*)d_ws + off;
        off += (bytes + 255) / 256 * 256;
        return p;
    };
    float* deg    = (float*)alloc((size_t)N_NODES * 4);       // becomes dinv in-place
    int*   counts = (int*)  alloc((size_t)N_NODES * 4);
    int*   rowp   = (int*)  alloc((size_t)(N_NODES + 1) * 4);
    int*   cursor = (int*)  alloc((size_t)N_NODES * 4);
    int*   col    = (int*)  alloc((size_t)N_EDGES * 4);
    float* nrm    = (float*)alloc((size_t)N_EDGES * 4);
    float* bufA   = (float*)alloc((size_t)N_NODES * 128 * 4); // t1 then t2
    float* bufB   = (float*)alloc((size_t)N_NODES * 128 * 4); // h1 then h2
    float* scores = (float*)alloc((size_t)N_NODES * 4);
    float* q      = (float*)alloc(D_CAT * 4);
    float* colsum = (float*)alloc(D_CAT * 4);
    float* cand_s = (float*)alloc((size_t)N_CAND * 4);
    int*   cand_i = (int*)  alloc((size_t)N_CAND * 4);

    int nblk = (N_NODES + 255) / 256;     // 196
    int eblk = (N_EDGES + 255) / 256;     // 2344

    hipLaunchKernelGGL(k_init, dim3(nblk), dim3(256), 0, stream, deg, counts, colsum, q);
    hipLaunchKernelGGL(k_deg, dim3(eblk), dim3(256), 0, stream, e_dst, ew, deg, counts);
    hipLaunchKernelGGL(k_dinv, dim3(nblk), dim3(256), 0, stream, deg);
    hipLaunchKernelGGL(k_scan, dim3(1), dim3(1024), 0, stream, counts, rowp, cursor);
    hipLaunchKernelGGL(k_fill, dim3(eblk), dim3(256), 0, stream, e_src, e_dst, ew, deg,
                       cursor, col, nrm);
    // conv1: t1 = x @ W1 ; h1 = relu(agg(t1) + b1)
    hipLaunchKernelGGL(k_gemm, dim3((N_NODES + BM - 1) / BM), dim3(256), 0, stream,
                       x, D_IN, x, 0, W1, bufA);
    hipLaunchKernelGGL(k_agg, dim3(N_NODES / 8), dim3(256), 0, stream,
                       bufA, deg, rowp, col, nrm, b1, bufB, 1);
    // conv2: t2 = [h1|attr] @ W2 ; h2 = agg(t2) + b2
    hipLaunchKernelGGL(k_gemm, dim3((N_NODES + BM - 1) / BM), dim3(256), 0, stream,
                       bufB, D_MID, attr, D_ATTR, W2, bufA);
    hipLaunchKernelGGL(k_agg, dim3(N_NODES / 8), dim3(256), 0, stream,
                       bufA, deg, rowp, col, nrm, b2, bufB, 0);
    // epilogue
    hipLaunchKernelGGL(k_q, dim3(8), dim3(192), 0, stream, hs, Wattn, q);
    hipLaunchKernelGGL(k_scores, dim3(N_NODES / 8), dim3(256), 0, stream,
                       bufB, attr, q, scores);
    hipLaunchKernelGGL(k_colsum, dim3(256), dim3(192), 0, stream, bufB, attr, colsum);
    hipLaunchKernelGGL(k_top1, dim3(N_CHUNKBLKS), dim3(256), 0, stream,
                       scores, cand_s, cand_i);
    hipLaunchKernelGGL(k_final, dim3(1), dim3(256), 0, stream,
                       cand_s, cand_i, bufB, attr, colsum, Wmap, bmap, out);
}

// Round 2
// 460.642 us; speedup vs baseline: 1.1904x; 1.1904x over previous
//
#include <hip/hip_runtime.h>

#define N_NODES 50000
#define N_EDGES 600000
#define D_IN 128
#define D_MID 128
#define D_ATTR 32
#define D_OUT 128
#define D_EMB 256
#define D_H 768
#define K_TOP 16
#define D_CAT (D_OUT + D_ATTR)   // 160
#define N_CHUNKBLKS 196          // ceil(50000/256)

// ---------------------------------------------------------------- init
__global__ void k_init(float* deg, int* counts, float* colsum, float* q) {
    int i = blockIdx.x * blockDim.x + threadIdx.x;
    if (i < N_NODES) { deg[i] = 1.0f; counts[i] = 0; }
    if (i < D_CAT)   { colsum[i] = 0.0f; q[i] = 0.0f; }
}

// ---------------------------------------------------------------- degree + histogram
__global__ void k_deg(const int* __restrict__ dst, const float* __restrict__ w,
                      float* deg, int* counts) {
    int e = blockIdx.x * blockDim.x + threadIdx.x;
    if (e < N_EDGES) {
        int d = dst[e];
        atomicAdd(&deg[d], w[e]);
        atomicAdd(&counts[d], 1);
    }
}

__global__ void k_dinv(float* deg) {
    int i = blockIdx.x * blockDim.x + threadIdx.x;
    if (i < N_NODES) deg[i] = rsqrtf(deg[i]);   // deg >= 1 always (self loop)
}

// ---------------------------------------------------------------- two-level scan
// stage 1: per-block inclusive scan of counts, emit block sums
__global__ __launch_bounds__(256) void k_scan_blk(const int* __restrict__ counts,
                                                  int* __restrict__ incl,
                                                  int* __restrict__ bsum) {
    __shared__ int sm[256];
    int tid = threadIdx.x;
    int i = blockIdx.x * 256 + tid;
    int v = (i < N_NODES) ? counts[i] : 0;
    sm[tid] = v;
    __syncthreads();
    for (int off = 1; off < 256; off <<= 1) {
        int t = (tid >= off) ? sm[tid - off] : 0;
        __syncthreads();
        sm[tid] += t;
        __syncthreads();
    }
    if (i < N_NODES) incl[i] = sm[tid];
    if (tid == 255) bsum[blockIdx.x] = sm[255];
}

// stage 2: scan the 196 block sums -> exclusive block offsets
__global__ __launch_bounds__(256) void k_scan_top(const int* __restrict__ bsum,
                                                  int* __restrict__ boff) {
    __shared__ int sm[256];
    int tid = threadIdx.x;
    int v = (tid < N_CHUNKBLKS) ? bsum[tid] : 0;
    sm[tid] = v;
    __syncthreads();
    for (int off = 1; off < 256; off <<= 1) {
        int t = (tid >= off) ? sm[tid - off] : 0;
        __syncthreads();
        sm[tid] += t;
        __syncthreads();
    }
    if (tid < N_CHUNKBLKS) boff[tid] = sm[tid] - v;   // exclusive
}

// stage 3: combine -> row_ptr, cursor
__global__ __launch_bounds__(256) void k_scan_add(const int* __restrict__ incl,
                                                  const int* __restrict__ boff,
                                                  const int* __restrict__ counts,
                                                  int* __restrict__ row_ptr,
                                                  int* __restrict__ cursor) {
    int i = blockIdx.x * 256 + threadIdx.x;
    if (i < N_NODES) {
        int ip = incl[i] + boff[blockIdx.x];
        row_ptr[i + 1] = ip;
        cursor[i] = ip - counts[i];
        if (i == 0) row_ptr[0] = 0;
    }
}

// ---------------------------------------------------------------- CSR fill
__global__ void k_fill(const int* __restrict__ src, const int* __restrict__ dst,
                       const float* __restrict__ w, const float* __restrict__ dinv,
                       int* __restrict__ cursor, int* __restrict__ col,
                       float* __restrict__ nrm) {
    int e = blockIdx.x * blockDim.x + threadIdx.x;
    if (e < N_EDGES) {
        int s = src[e], d = dst[e];
        int pos = atomicAdd(&cursor[d], 1);
        col[pos] = s;
        nrm[pos] = dinv[s] * w[e] * dinv[d];
    }
}

// ---------------------------------------------------------------- GEMM: out[N,128] = [in1|in2] @ W
#define BM 64
#define KT 32
__global__ __launch_bounds__(256) void k_gemm(
    const float* __restrict__ in1, int d1,
    const float* __restrict__ in2, int d2,
    const float* __restrict__ W,      // [(d1+d2) x 128]
    float* __restrict__ out)          // [N x 128]
{
    __shared__ float xs[BM][KT + 1];
    __shared__ float ws[KT][128];
    int tid = threadIdx.x;
    int cx = tid & 15;        // col group: cols cx*8 .. cx*8+7
    int ry = tid >> 4;        // row group: rows ry*4 .. ry*4+3
    int row0 = blockIdx.x * BM;
    float acc[4][8];
#pragma unroll
    for (int a = 0; a < 4; a++)
#pragma unroll
        for (int b = 0; b < 8; b++) acc[a][b] = 0.0f;
    int KD = d1 + d2;
    for (int kt = 0; kt < KD; kt += KT) {
        for (int idx = tid; idx < BM * KT; idx += 256) {
            int rr = idx >> 5;        // KT == 32
            int kk = idx & 31;
            int r = row0 + rr, kg = kt + kk;
            float v = 0.0f;
            if (r < N_NODES)
                v = (kg < d1) ? in1[r * d1 + kg] : in2[r * d2 + (kg - d1)];
            xs[rr][kk] = v;
        }
        for (int idx = tid; idx < KT * 128; idx += 256) {
            int kk = idx >> 7;
            int c = idx & 127;
            ws[kk][c] = W[(kt + kk) * 128 + c];
        }
        __syncthreads();
#pragma unroll
        for (int kk = 0; kk < KT; ++kk) {
            float x0 = xs[ry * 4 + 0][kk];
            float x1 = xs[ry * 4 + 1][kk];
            float x2 = xs[ry * 4 + 2][kk];
            float x3 = xs[ry * 4 + 3][kk];
            float wv[8];
#pragma unroll
            for (int j = 0; j < 8; j++) wv[j] = ws[kk][cx * 8 + j];
#pragma unroll
            for (int j = 0; j < 8; j++) {
                acc[0][j] += x0 * wv[j];
                acc[1][j] += x1 * wv[j];
                acc[2][j] += x2 * wv[j];
                acc[3][j] += x3 * wv[j];
            }
        }
        __syncthreads();
    }
    for (int rr = 0; rr < 4; ++rr) {
        int r = row0 + ry * 4 + rr;
        if (r < N_NODES) {
            float4 v0 = make_float4(acc[rr][0], acc[rr][1], acc[rr][2], acc[rr][3]);
            float4 v1 = make_float4(acc[rr][4], acc[rr][5], acc[rr][6], acc[rr][7]);
            float4* o = (float4*)(out + r * 128 + cx * 8);
            o[0] = v0;
            o[1] = v1;
        }
    }
}

// ---------------------------------------------------------------- aggregation (CSR gather)
__global__ __launch_bounds__(256) void k_agg(
    const float* __restrict__ t, const float* __restrict__ dinv,
    const int* __restrict__ row_ptr, const int* __restrict__ col,
    const float* __restrict__ nrm, const float* __restrict__ bias,
    float* __restrict__ out, int relu_flag)
{
    int lane = threadIdx.x & 31;
    int node = blockIdx.x * 8 + (threadIdx.x >> 5);
    if (node >= N_NODES) return;
    const float4* t4 = (const float4*)t;
    float di = dinv[node];
    float sw = di * di;
    float4 v = t4[node * 32 + lane];
    float4 acc;
    acc.x = v.x * sw; acc.y = v.y * sw; acc.z = v.z * sw; acc.w = v.w * sw;
    int e0 = row_ptr[node], e1 = row_ptr[node + 1];
    for (int e = e0; e < e1; ++e) {
        int s = col[e];
        float wn = nrm[e];
        float4 u = t4[s * 32 + lane];
        acc.x += wn * u.x; acc.y += wn * u.y; acc.z += wn * u.z; acc.w += wn * u.w;
    }
    const float4* b4 = (const float4*)bias;
    float4 bb = b4[lane];
    acc.x += bb.x; acc.y += bb.y; acc.z += bb.z; acc.w += bb.w;
    if (relu_flag) {
        acc.x = fmaxf(acc.x, 0.0f); acc.y = fmaxf(acc.y, 0.0f);
        acc.z = fmaxf(acc.z, 0.0f); acc.w = fmaxf(acc.w, 0.0f);
    }
    ((float4*)out)[node * 32 + lane] = acc;
}

// ---------------------------------------------------------------- q = hidden_state @ Wattn  [160]
__global__ void k_q(const float* __restrict__ hs, const float* __restrict__ Wattn,
                    float* __restrict__ q) {
    int j = threadIdx.x;
    if (j >= D_CAT) return;
    int k0 = blockIdx.x * (D_H / 8);       // grid 8
    float acc = 0.0f;
    for (int k = k0; k < k0 + D_H / 8; k++) acc += hs[k] * Wattn[k * D_CAT + j];
    atomicAdd(&q[j], acc);
}

// ---------------------------------------------------------------- scores = [h2|attr] . q
__global__ __launch_bounds__(256) void k_scores(
    const float* __restrict__ h2, const float* __restrict__ attr,
    const float* __restrict__ q, float* __restrict__ scores)
{
    int lane = threadIdx.x & 31;
    int node = blockIdx.x * 8 + (threadIdx.x >> 5);
    if (node >= N_NODES) return;
    const float4* h4 = (const float4*)h2;
    const float4* q4 = (const float4*)q;
    float4 a = h4[node * 32 + lane];
    float4 qq = q4[lane];
    float s = a.x * qq.x + a.y * qq.y + a.z * qq.z + a.w * qq.w;
    if (lane < 8) {
        const float4* at4 = (const float4*)attr;
        float4 b = at4[node * 8 + lane];
        float4 q2 = q4[32 + lane];
        s += b.x * q2.x + b.y * q2.y + b.z * q2.z + b.w * q2.w;
    }
    for (int off = 16; off; off >>= 1) s += __shfl_xor(s, off, 32);
    if (lane == 0) scores[node] = s;
}

// ---------------------------------------------------------------- column sums for mean pool
__global__ void k_colsum(const float* __restrict__ h2, const float* __restrict__ attr,
                         float* __restrict__ colsum) {
    int j = threadIdx.x;
    int per = (N_NODES + gridDim.x - 1) / gridDim.x;
    int r0 = blockIdx.x * per;
    int r1 = min(N_NODES, r0 + per);
    float acc = 0.0f;
    if (j < D_OUT) {
        for (int i = r0; i < r1; i++) acc += h2[i * D_OUT + j];
        atomicAdd(&colsum[j], acc);
    } else if (j < D_CAT) {
        int jj = j - D_OUT;
        for (int i = r0; i < r1; i++) acc += attr[i * D_ATTR + jj];
        atomicAdd(&colsum[j], acc);
    }
}

// ---------------------------------------------------------------- top-k stage 1
__global__ __launch_bounds__(256) void k_top1(const float* __restrict__ scores,
                                              float* __restrict__ cand_s,
                                              int* __restrict__ cand_i) {
    __shared__ float ss[256];
    __shared__ int si[256];
    __shared__ float rs[256];
    __shared__ int ri[256];
    int tid = threadIdx.x;
    int i = blockIdx.x * 256 + tid;
    ss[tid] = (i < N_NODES) ? scores[i] : -INFINITY;
    si[tid] = i;
    __syncthreads();
    for (int it = 0; it < K_TOP; ++it) {
        rs[tid] = ss[tid]; ri[tid] = si[tid];
        __syncthreads();
        for (int off = 128; off; off >>= 1) {
            if (tid < off) {
                float s2 = rs[tid + off]; int i2 = ri[tid + off];
                if (s2 > rs[tid] || (s2 == rs[tid] && i2 < ri[tid])) { rs[tid] = s2; ri[tid] = i2; }
            }
            __syncthreads();
        }
        if (tid == 0) {
            cand_s[blockIdx.x * K_TOP + it] = rs[0];
            cand_i[blockIdx.x * K_TOP + it] = ri[0];
        }
        __syncthreads();
        if (si[tid] == ri[0]) ss[tid] = -INFINITY;
        __syncthreads();
    }
}

// ---------------------------------------------------------------- stage 2 + emb + gather
#define N_CAND (N_CHUNKBLKS * K_TOP)   // 3136
__global__ __launch_bounds__(256) void k_final(
    const float* __restrict__ cand_s, const int* __restrict__ cand_i,
    const float* __restrict__ h2, const float* __restrict__ attr,
    const float* __restrict__ colsum, const float* __restrict__ Wmap,
    const float* __restrict__ bmap, float* __restrict__ out)
{
    __shared__ float ss[4096];
    __shared__ int si[4096];
    __shared__ float rs[256];
    __shared__ int ri[256];
    __shared__ int topidx[K_TOP];
    int tid = threadIdx.x;
    for (int i = tid; i < 4096; i += 256) {
        ss[i] = (i < N_CAND) ? cand_s[i] : -INFINITY;
        si[i] = (i < N_CAND) ? cand_i[i] : 0x7fffffff;
    }
    __syncthreads();
    for (int it = 0; it < K_TOP; ++it) {
        float bs = -INFINITY; int bi = 0x7fffffff;
        for (int i = tid; i < 4096; i += 256) {
            float s = ss[i]; int ii = si[i];
            if (s > bs || (s == bs && ii < bi)) { bs = s; bi = ii; }
        }
        rs[tid] = bs; ri[tid] = bi;
        __syncthreads();
        for (int off = 128; off; off >>= 1) {
            if (tid < off) {
                float s2 = rs[tid + off]; int i2 = ri[tid + off];
                if (s2 > rs[tid] || (s2 == rs[tid] && i2 < ri[tid])) { rs[tid] = s2; ri[tid] = i2; }
            }
            __syncthreads();
        }
        if (tid == 0) topidx[it] = ri[0];
        __syncthreads();
        for (int i = tid; i < 4096; i += 256)
            if (si[i] == ri[0]) ss[i] = -INFINITY;
        __syncthreads();
    }
    // emb = (colsum / N) @ Wmap + bmap  -> out[0:256]
    {
        float acc = 0.0f;
        for (int k = 0; k < D_CAT; k++) acc += colsum[k] * Wmap[k * D_EMB + tid];
        out[tid] = acc * (1.0f / N_NODES) + bmap[tid];
    }
    __syncthreads();
    // chose_nodes gather -> out[256 : 256 + 16*160]
    for (int idx = tid; idx < K_TOP * D_CAT; idx += 256) {
        int kk = idx / D_CAT;
        int d = idx % D_CAT;
        int node = topidx[kk];
        out[D_EMB + idx] = (d < D_OUT) ? h2[node * D_OUT + d]
                                       : attr[node * D_ATTR + (d - D_OUT)];
    }
}

// ================================================================ host
extern "C" void kernel_launch(void* const* d_in, const int* in_sizes, int n_in,
                              void* d_out, int out_size, void* d_ws, size_t ws_size,
                              hipStream_t stream) {
    const float* x      = (const float*)d_in[0];
    const float* attr   = (const float*)d_in[1];
    const float* ew     = (const float*)d_in[2];
    const float* hs     = (const float*)d_in[3];
    const int*   ei     = (const int*)d_in[4];      // [2,E] int32: row0=src, row1=dst
    const float* W1     = (const float*)d_in[5];
    const float* b1     = (const float*)d_in[6];
    const float* W2     = (const float*)d_in[7];
    const float* b2     = (const float*)d_in[8];
    const float* Wmap   = (const float*)d_in[9];
    const float* bmap   = (const float*)d_in[10];
    const float* Wattn  = (const float*)d_in[11];
    float* out = (float*)d_out;
    const int* e_src = ei;
    const int* e_dst = ei + N_EDGES;

    size_t off = 0;
    auto alloc = [&](size_t bytes) {
        void* p = (char*)d_ws + off;
        off += (bytes + 255) / 256 * 256;
        return p;
    };
    float* deg    = (float*)alloc((size_t)N_NODES * 4);       // becomes dinv in-place
    int*   counts = (int*)  alloc((size_t)N_NODES * 4);
    int*   rowp   = (int*)  alloc((size_t)(N_NODES + 1) * 4);
    int*   cursor = (int*)  alloc((size_t)N_NODES * 4);
    int*   col    = (int*)  alloc((size_t)N_EDGES * 4);
    float* nrm    = (float*)alloc((size_t)N_EDGES * 4);
    float* bufA   = (float*)alloc((size_t)N_NODES * 128 * 4); // t1 then t2
    float* bufB   = (float*)alloc((size_t)N_NODES * 128 * 4); // h1 then h2
    float* scores = (float*)alloc((size_t)N_NODES * 4);
    float* q      = (float*)alloc(D_CAT * 4);
    float* colsum = (float*)alloc(D_CAT * 4);
    float* cand_s = (float*)alloc((size_t)N_CAND * 4);
    int*   cand_i = (int*)  alloc((size_t)N_CAND * 4);
    int*   incl   = (int*)  alloc((size_t)N_NODES * 4);
    int*   bsum   = (int*)  alloc((size_t)N_CHUNKBLKS * 4);
    int*   boff   = (int*)  alloc((size_t)N_CHUNKBLKS * 4);

    int nblk = (N_NODES + 255) / 256;     // 196
    int eblk = (N_EDGES + 255) / 256;     // 2344

    hipLaunchKernelGGL(k_init, dim3(nblk), dim3(256), 0, stream, deg, counts, colsum, q);
    hipLaunchKernelGGL(k_deg, dim3(eblk), dim3(256), 0, stream, e_dst, ew, deg, counts);
    hipLaunchKernelGGL(k_dinv, dim3(nblk), dim3(256), 0, stream, deg);
    hipLaunchKernelGGL(k_scan_blk, dim3(nblk), dim3(256), 0, stream, counts, incl, bsum);
    hipLaunchKernelGGL(k_scan_top, dim3(1), dim3(256), 0, stream, bsum, boff);
    hipLaunchKernelGGL(k_scan_add, dim3(nblk), dim3(256), 0, stream, incl, boff, counts,
                       rowp, cursor);
    hipLaunchKernelGGL(k_fill, dim3(eblk), dim3(256), 0, stream, e_src, e_dst, ew, deg,
                       cursor, col, nrm);
    // conv1: t1 = x @ W1 ; h1 = relu(agg(t1) + b1)
    hipLaunchKernelGGL(k_gemm, dim3((N_NODES + BM - 1) / BM), dim3(256), 0, stream,
                       x, D_IN, x, 0, W1, bufA);
    hipLaunchKernelGGL(k_agg, dim3(N_NODES / 8), dim3(256), 0, stream,
                       bufA, deg, rowp, col, nrm, b1, bufB, 1);
    // conv2: t2 = [h1|attr] @ W2 ; h2 = agg(t2) + b2
    hipLaunchKernelGGL(k_gemm, dim3((N_NODES + BM - 1) / BM), dim3(256), 0, stream,
                       bufB, D_MID, attr, D_ATTR, W2, bufA);
    hipLaunchKernelGGL(k_agg, dim3(N_NODES / 8), dim3(256), 0, stream,
                       bufA, deg, rowp, col, nrm, b2, bufB, 0);
    // epilogue
    hipLaunchKernelGGL(k_q, dim3(8), dim3(192), 0, stream, hs, Wattn, q);
    hipLaunchKernelGGL(k_scores, dim3(N_NODES / 8), dim3(256), 0, stream,
                       bufB, attr, q, scores);
    hipLaunchKernelGGL(k_colsum, dim3(256), dim3(192), 0, stream, bufB, attr, colsum);
    hipLaunchKernelGGL(k_top1, dim3(N_CHUNKBLKS), dim3(256), 0, stream,
                       scores, cand_s, cand_i);
    hipLaunchKernelGGL(k_final, dim3(1), dim3(256), 0, stream,
                       cand_s, cand_i, bufB, attr, colsum, Wmap, bmap, out);
}

// Round 3
// 417.903 us; speedup vs baseline: 1.3121x; 1.1023x over previous
//
#include <hip/hip_runtime.h>

#define N_NODES 50000
#define N_EDGES 600000
#define D_IN 128
#define D_MID 128
#define D_ATTR 32
#define D_OUT 128
#define D_EMB 256
#define D_H 768
#define K_TOP 16
#define D_CAT (D_OUT + D_ATTR)   // 160
#define N_CHUNKBLKS 196          // ceil(50000/256)
#define N_CAND (N_CHUNKBLKS * K_TOP)   // 3136
#define CSLOTS 13                // ceil(3136/256)

// ---------------------------------------------------------------- init
__global__ void k_init(float* deg, int* counts, float* colsum, float* q) {
    int i = blockIdx.x * blockDim.x + threadIdx.x;
    if (i < N_NODES) { deg[i] = 1.0f; counts[i] = 0; }
    if (i < D_CAT)   { colsum[i] = 0.0f; q[i] = 0.0f; }
}

// ---------------------------------------------------------------- degree + histogram
__global__ void k_deg(const int* __restrict__ dst, const float* __restrict__ w,
                      float* deg, int* counts) {
    int e = blockIdx.x * blockDim.x + threadIdx.x;
    if (e < N_EDGES) {
        int d = dst[e];
        atomicAdd(&deg[d], w[e]);
        atomicAdd(&counts[d], 1);
    }
}

__global__ void k_dinv(float* deg) {
    int i = blockIdx.x * blockDim.x + threadIdx.x;
    if (i < N_NODES) deg[i] = rsqrtf(deg[i]);   // deg >= 1 always (self loop)
}

// ---------------------------------------------------------------- two-level scan
__global__ __launch_bounds__(256) void k_scan_blk(const int* __restrict__ counts,
                                                  int* __restrict__ incl,
                                                  int* __restrict__ bsum) {
    __shared__ int sm[256];
    int tid = threadIdx.x;
    int i = blockIdx.x * 256 + tid;
    int v = (i < N_NODES) ? counts[i] : 0;
    sm[tid] = v;
    __syncthreads();
    for (int off = 1; off < 256; off <<= 1) {
        int t = (tid >= off) ? sm[tid - off] : 0;
        __syncthreads();
        sm[tid] += t;
        __syncthreads();
    }
    if (i < N_NODES) incl[i] = sm[tid];
    if (tid == 255) bsum[blockIdx.x] = sm[255];
}

__global__ __launch_bounds__(256) void k_scan_top(const int* __restrict__ bsum,
                                                  int* __restrict__ boff) {
    __shared__ int sm[256];
    int tid = threadIdx.x;
    int v = (tid < N_CHUNKBLKS) ? bsum[tid] : 0;
    sm[tid] = v;
    __syncthreads();
    for (int off = 1; off < 256; off <<= 1) {
        int t = (tid >= off) ? sm[tid - off] : 0;
        __syncthreads();
        sm[tid] += t;
        __syncthreads();
    }
    if (tid < N_CHUNKBLKS) boff[tid] = sm[tid] - v;   // exclusive
}

__global__ __launch_bounds__(256) void k_scan_add(const int* __restrict__ incl,
                                                  const int* __restrict__ boff,
                                                  const int* __restrict__ counts,
                                                  int* __restrict__ row_ptr,
                                                  int* __restrict__ cursor) {
    int i = blockIdx.x * 256 + threadIdx.x;
    if (i < N_NODES) {
        int ip = incl[i] + boff[blockIdx.x];
        row_ptr[i + 1] = ip;
        cursor[i] = ip - counts[i];
        if (i == 0) row_ptr[0] = 0;
    }
}

// ---------------------------------------------------------------- CSR fill
__global__ void k_fill(const int* __restrict__ src, const int* __restrict__ dst,
                       const float* __restrict__ w, const float* __restrict__ dinv,
                       int* __restrict__ cursor, int* __restrict__ col,
                       float* __restrict__ nrm) {
    int e = blockIdx.x * blockDim.x + threadIdx.x;
    if (e < N_EDGES) {
        int s = src[e], d = dst[e];
        int pos = atomicAdd(&cursor[d], 1);
        col[pos] = s;
        nrm[pos] = dinv[s] * w[e] * dinv[d];
    }
}

// ---------------------------------------------------------------- GEMM: out[N,128] = [in1|in2] @ W
#define BM 64
#define KT 32
__global__ __launch_bounds__(256) void k_gemm(
    const float* __restrict__ in1, int d1,
    const float* __restrict__ in2, int d2,
    const float* __restrict__ W,      // [(d1+d2) x 128]
    float* __restrict__ out)          // [N x 128]
{
    __shared__ float xs[BM][KT + 1];
    __shared__ float ws[KT][128];
    int tid = threadIdx.x;
    int cx = tid & 15;
    int ry = tid >> 4;
    int row0 = blockIdx.x * BM;
    float acc[4][8];
#pragma unroll
    for (int a = 0; a < 4; a++)
#pragma unroll
        for (int b = 0; b < 8; b++) acc[a][b] = 0.0f;
    int KD = d1 + d2;
    for (int kt = 0; kt < KD; kt += KT) {
        for (int idx = tid; idx < BM * KT; idx += 256) {
            int rr = idx >> 5;
            int kk = idx & 31;
            int r = row0 + rr, kg = kt + kk;
            float v = 0.0f;
            if (r < N_NODES)
                v = (kg < d1) ? in1[r * d1 + kg] : in2[r * d2 + (kg - d1)];
            xs[rr][kk] = v;
        }
        for (int idx = tid; idx < KT * 128; idx += 256) {
            int kk = idx >> 7;
            int c = idx & 127;
            ws[kk][c] = W[(kt + kk) * 128 + c];
        }
        __syncthreads();
#pragma unroll
        for (int kk = 0; kk < KT; ++kk) {
            float x0 = xs[ry * 4 + 0][kk];
            float x1 = xs[ry * 4 + 1][kk];
            float x2 = xs[ry * 4 + 2][kk];
            float x3 = xs[ry * 4 + 3][kk];
            float wv[8];
#pragma unroll
            for (int j = 0; j < 8; j++) wv[j] = ws[kk][cx * 8 + j];
#pragma unroll
            for (int j = 0; j < 8; j++) {
                acc[0][j] += x0 * wv[j];
                acc[1][j] += x1 * wv[j];
                acc[2][j] += x2 * wv[j];
                acc[3][j] += x3 * wv[j];
            }
        }
        __syncthreads();
    }
    for (int rr = 0; rr < 4; ++rr) {
        int r = row0 + ry * 4 + rr;
        if (r < N_NODES) {
            float4 v0 = make_float4(acc[rr][0], acc[rr][1], acc[rr][2], acc[rr][3]);
            float4 v1 = make_float4(acc[rr][4], acc[rr][5], acc[rr][6], acc[rr][7]);
            float4* o = (float4*)(out + r * 128 + cx * 8);
            o[0] = v0;
            o[1] = v1;
        }
    }
}

// ---------------------------------------------------------------- aggregation (CSR gather)
// out = sum nrm*t[col] + dinv^2*t[node] + bias; optionally relu, optionally fused score
__global__ __launch_bounds__(256) void k_agg(
    const float* __restrict__ t, const float* __restrict__ dinv,
    const int* __restrict__ row_ptr, const int* __restrict__ col,
    const float* __restrict__ nrm, const float* __restrict__ bias,
    float* __restrict__ out, int relu_flag,
    const float* __restrict__ attr, const float* __restrict__ q,
    float* __restrict__ scores, int score_flag)
{
    int lane = threadIdx.x & 31;
    int node = blockIdx.x * 8 + (threadIdx.x >> 5);
    if (node >= N_NODES) return;
    const float4* t4 = (const float4*)t;
    float di = dinv[node];
    float sw = di * di;
    float4 v = t4[node * 32 + lane];
    float4 acc;
    acc.x = v.x * sw; acc.y = v.y * sw; acc.z = v.z * sw; acc.w = v.w * sw;
    int e0 = row_ptr[node], e1 = row_ptr[node + 1];
    for (int e = e0; e < e1; ++e) {
        int s = col[e];
        float wn = nrm[e];
        float4 u = t4[s * 32 + lane];
        acc.x += wn * u.x; acc.y += wn * u.y; acc.z += wn * u.z; acc.w += wn * u.w;
    }
    const float4* b4 = (const float4*)bias;
    float4 bb = b4[lane];
    acc.x += bb.x; acc.y += bb.y; acc.z += bb.z; acc.w += bb.w;
    if (relu_flag) {
        acc.x = fmaxf(acc.x, 0.0f); acc.y = fmaxf(acc.y, 0.0f);
        acc.z = fmaxf(acc.z, 0.0f); acc.w = fmaxf(acc.w, 0.0f);
    }
    ((float4*)out)[node * 32 + lane] = acc;
    if (score_flag) {
        const float4* q4 = (const float4*)q;
        float4 qq = q4[lane];
        float s = acc.x * qq.x + acc.y * qq.y + acc.z * qq.z + acc.w * qq.w;
        if (lane < 8) {
            const float4* at4 = (const float4*)attr;
            float4 b = at4[node * 8 + lane];
            float4 q2 = q4[32 + lane];
            s += b.x * q2.x + b.y * q2.y + b.z * q2.z + b.w * q2.w;
        }
        for (int off = 16; off; off >>= 1) s += __shfl_xor(s, off, 32);
        if (lane == 0) scores[node] = s;
    }
}

// ---------------------------------------------------------------- q = hidden_state @ Wattn  [160]
__global__ void k_q(const float* __restrict__ hs, const float* __restrict__ Wattn,
                    float* __restrict__ q) {
    int j = threadIdx.x;
    if (j >= D_CAT) return;
    int k0 = blockIdx.x * (D_H / 8);       // grid 8
    float acc = 0.0f;
    for (int k = k0; k < k0 + D_H / 8; k++) acc += hs[k] * Wattn[k * D_CAT + j];
    atomicAdd(&q[j], acc);
}

// ---------------------------------------------------------------- column sums for mean pool
__global__ void k_colsum(const float* __restrict__ h2, const float* __restrict__ attr,
                         float* __restrict__ colsum) {
    int j = threadIdx.x;
    int per = (N_NODES + gridDim.x - 1) / gridDim.x;
    int r0 = blockIdx.x * per;
    int r1 = min(N_NODES, r0 + per);
    float acc = 0.0f;
    if (j < D_OUT) {
        for (int i = r0; i < r1; i++) acc += h2[i * D_OUT + j];
        atomicAdd(&colsum[j], acc);
    } else if (j < D_CAT) {
        int jj = j - D_OUT;
        for (int i = r0; i < r1; i++) acc += attr[i * D_ATTR + jj];
        atomicAdd(&colsum[j], acc);
    }
}

// ---------------------------------------------------------------- top-k stage 1
__global__ __launch_bounds__(256) void k_top1(const float* __restrict__ scores,
                                              float* __restrict__ cand_s,
                                              int* __restrict__ cand_i) {
    __shared__ float ss[256];
    __shared__ int si[256];
    __shared__ float rs[256];
    __shared__ int ri[256];
    int tid = threadIdx.x;
    int i = blockIdx.x * 256 + tid;
    ss[tid] = (i < N_NODES) ? scores[i] : -INFINITY;
    si[tid] = i;
    __syncthreads();
    for (int it = 0; it < K_TOP; ++it) {
        rs[tid] = ss[tid]; ri[tid] = si[tid];
        __syncthreads();
        for (int off = 128; off; off >>= 1) {
            if (tid < off) {
                float s2 = rs[tid + off]; int i2 = ri[tid + off];
                if (s2 > rs[tid] || (s2 == rs[tid] && i2 < ri[tid])) { rs[tid] = s2; ri[tid] = i2; }
            }
            __syncthreads();
        }
        if (tid == 0) {
            cand_s[blockIdx.x * K_TOP + it] = rs[0];
            cand_i[blockIdx.x * K_TOP + it] = ri[0];
        }
        __syncthreads();
        if (si[tid] == ri[0]) ss[tid] = -INFINITY;
        __syncthreads();
    }
}

// ---------------------------------------------------------------- top-k stage 2: register-resident
__global__ __launch_bounds__(256) void k_top2(const float* __restrict__ cand_s,
                                              const int* __restrict__ cand_i,
                                              int* __restrict__ topidx) {
    float s[CSLOTS]; int ix[CSLOTS];
    int tid = threadIdx.x;
    int lane = tid & 63;
    int wave = tid >> 6;
#pragma unroll
    for (int j = 0; j < CSLOTS; ++j) {
        int c = tid + j * 256;
        s[j]  = (c < N_CAND) ? cand_s[c] : -INFINITY;
        ix[j] = (c < N_CAND) ? cand_i[c] : 0x7fffffff;
    }
    __shared__ float wsum_s[4];
    __shared__ int   wsum_i[4];
    __shared__ float win_s;
    __shared__ int   win_i;
    for (int it = 0; it < K_TOP; ++it) {
        float bs = -INFINITY; int bi = 0x7fffffff;
#pragma unroll
        for (int j = 0; j < CSLOTS; ++j) {
            if (s[j] > bs || (s[j] == bs && ix[j] < bi)) { bs = s[j]; bi = ix[j]; }
        }
#pragma unroll
        for (int off = 32; off; off >>= 1) {
            float s2 = __shfl_xor(bs, off, 64);
            int   i2 = __shfl_xor(bi, off, 64);
            if (s2 > bs || (s2 == bs && i2 < bi)) { bs = s2; bi = i2; }
        }
        if (lane == 0) { wsum_s[wave] = bs; wsum_i[wave] = bi; }
        __syncthreads();
        if (tid == 0) {
            float ws0 = wsum_s[0]; int wi0 = wsum_i[0];
#pragma unroll
            for (int w = 1; w < 4; ++w) {
                float s2 = wsum_s[w]; int i2 = wsum_i[w];
                if (s2 > ws0 || (s2 == ws0 && i2 < wi0)) { ws0 = s2; wi0 = i2; }
            }
            win_s = ws0; win_i = wi0;
            topidx[it] = wi0;
        }
        __syncthreads();
        int w = win_i;
#pragma unroll
        for (int j = 0; j < CSLOTS; ++j)
            if (ix[j] == w) s[j] = -INFINITY;
        __syncthreads();
    }
}

// ---------------------------------------------------------------- emb GEMV + top-node gather
__global__ __launch_bounds__(256) void k_emb_gather(
    const float* __restrict__ colsum, const float* __restrict__ Wmap,
    const float* __restrict__ bmap, const int* __restrict__ topidx,
    const float* __restrict__ h2, const float* __restrict__ attr,
    float* __restrict__ out)
{
    int tid = threadIdx.x;
    __shared__ float cs[D_CAT];
    if (tid < D_CAT) cs[tid] = colsum[tid];
    __syncthreads();
    float acc = 0.0f;
#pragma unroll 8
    for (int k = 0; k < D_CAT; ++k) acc += cs[k] * Wmap[k * D_EMB + tid];
    out[tid] = acc * (1.0f / N_NODES) + bmap[tid];
    // gather
    __shared__ int ti[K_TOP];
    if (tid < K_TOP) ti[tid] = topidx[tid];
    __syncthreads();
    for (int idx = tid; idx < K_TOP * D_CAT; idx += 256) {
        int kk = idx / D_CAT;
        int d = idx % D_CAT;
        int node = ti[kk];
        out[D_EMB + idx] = (d < D_OUT) ? h2[node * D_OUT + d]
                                       : attr[node * D_ATTR + (d - D_OUT)];
    }
}

// ================================================================ host
extern "C" void kernel_launch(void* const* d_in, const int* in_sizes, int n_in,
                              void* d_out, int out_size, void* d_ws, size_t ws_size,
                              hipStream_t stream) {
    const float* x      = (const float*)d_in[0];
    const float* attr   = (const float*)d_in[1];
    const float* ew     = (const float*)d_in[2];
    const float* hs     = (const float*)d_in[3];
    const int*   ei     = (const int*)d_in[4];
    const float* W1     = (const float*)d_in[5];
    const float* b1     = (const float*)d_in[6];
    const float* W2     = (const float*)d_in[7];
    const float* b2     = (const float*)d_in[8];
    const float* Wmap   = (const float*)d_in[9];
    const float* bmap   = (const float*)d_in[10];
    const float* Wattn  = (const float*)d_in[11];
    float* out = (float*)d_out;
    const int* e_src = ei;
    const int* e_dst = ei + N_EDGES;

    size_t off = 0;
    auto alloc = [&](size_t bytes) {
        void* p = (char*)d_ws + off;
        off += (bytes + 255) / 256 * 256;
        return p;
    };
    float* deg    = (float*)alloc((size_t)N_NODES * 4);
    int*   counts = (int*)  alloc((size_t)N_NODES * 4);
    int*   rowp   = (int*)  alloc((size_t)(N_NODES + 1) * 4);
    int*   cursor = (int*)  alloc((size_t)N_NODES * 4);
    int*   col    = (int*)  alloc((size_t)N_EDGES * 4);
    float* nrm    = (float*)alloc((size_t)N_EDGES * 4);
    float* bufA   = (float*)alloc((size_t)N_NODES * 128 * 4);
    float* bufB   = (float*)alloc((size_t)N_NODES * 128 * 4);
    float* scores = (float*)alloc((size_t)N_NODES * 4);
    float* q      = (float*)alloc(D_CAT * 4);
    float* colsum = (float*)alloc(D_CAT * 4);
    float* cand_s = (float*)alloc((size_t)N_CAND * 4);
    int*   cand_i = (int*)  alloc((size_t)N_CAND * 4);
    int*   incl   = (int*)  alloc((size_t)N_NODES * 4);
    int*   bsum   = (int*)  alloc((size_t)N_CHUNKBLKS * 4);
    int*   boff   = (int*)  alloc((size_t)N_CHUNKBLKS * 4);
    int*   topidx = (int*)  alloc((size_t)K_TOP * 4);

    int nblk = (N_NODES + 255) / 256;     // 196
    int eblk = (N_EDGES + 255) / 256;     // 2344

    hipLaunchKernelGGL(k_init, dim3(nblk), dim3(256), 0, stream, deg, counts, colsum, q);
    hipLaunchKernelGGL(k_deg, dim3(eblk), dim3(256), 0, stream, e_dst, ew, deg, counts);
    hipLaunchKernelGGL(k_dinv, dim3(nblk), dim3(256), 0, stream, deg);
    hipLaunchKernelGGL(k_scan_blk, dim3(nblk), dim3(256), 0, stream, counts, incl, bsum);
    hipLaunchKernelGGL(k_scan_top, dim3(1), dim3(256), 0, stream, bsum, boff);
    hipLaunchKernelGGL(k_scan_add, dim3(nblk), dim3(256), 0, stream, incl, boff, counts,
                       rowp, cursor);
    hipLaunchKernelGGL(k_fill, dim3(eblk), dim3(256), 0, stream, e_src, e_dst, ew, deg,
                       cursor, col, nrm);
    // q (independent, needed by fused score in second agg)
    hipLaunchKernelGGL(k_q, dim3(8), dim3(192), 0, stream, hs, Wattn, q);
    // conv1: t1 = x @ W1 ; h1 = relu(agg(t1) + b1)
    hipLaunchKernelGGL(k_gemm, dim3((N_NODES + BM - 1) / BM), dim3(256), 0, stream,
                       x, D_IN, x, 0, W1, bufA);
    hipLaunchKernelGGL(k_agg, dim3(N_NODES / 8), dim3(256), 0, stream,
                       bufA, deg, rowp, col, nrm, b1, bufB, 1,
                       (const float*)nullptr, (const float*)nullptr, (float*)nullptr, 0);
    // conv2: t2 = [h1|attr] @ W2 ; h2 = agg(t2) + b2 ; fused scores
    hipLaunchKernelGGL(k_gemm, dim3((N_NODES + BM - 1) / BM), dim3(256), 0, stream,
                       bufB, D_MID, attr, D_ATTR, W2, bufA);
    hipLaunchKernelGGL(k_agg, dim3(N_NODES / 8), dim3(256), 0, stream,
                       bufA, deg, rowp, col, nrm, b2, bufB, 0,
                       attr, q, scores, 1);
    // epilogue
    hipLaunchKernelGGL(k_colsum, dim3(256), dim3(192), 0, stream, bufB, attr, colsum);
    hipLaunchKernelGGL(k_top1, dim3(N_CHUNKBLKS), dim3(256), 0, stream,
                       scores, cand_s, cand_i);
    hipLaunchKernelGGL(k_top2, dim3(1), dim3(256), 0, stream, cand_s, cand_i, topidx);
    hipLaunchKernelGGL(k_emb_gather, dim3(1), dim3(256), 0, stream,
                       colsum, Wmap, bmap, topidx, bufB, attr, out);
}

// Round 4
// 382.312 us; speedup vs baseline: 1.4343x; 1.0931x over previous
//
#include <hip/hip_runtime.h>

#define N_NODES 50000
#define N_EDGES 600000
#define D_IN 128
#define D_MID 128
#define D_ATTR 32
#define D_OUT 128
#define D_EMB 256
#define D_H 768
#define K_TOP 16
#define D_CAT (D_OUT + D_ATTR)   // 160
#define N_CHUNKBLKS 196          // ceil(50000/256)
#define N_CAND (N_CHUNKBLKS * K_TOP)   // 3136
#define CSLOTS 13                // ceil(3136/256)
#define WSCALE 262144.0f         // 2^18 fixed-point for packed degree

// ---------------------------------------------------------------- init
__global__ void k_init(unsigned long long* packed, float* colsum, float* q) {
    int i = blockIdx.x * blockDim.x + threadIdx.x;
    if (i < N_NODES) packed[i] = 0ULL;
    if (i < D_CAT)   { colsum[i] = 0.0f; q[i] = 0.0f; }
}

// ---------------------------------------------------------------- packed degree+count
__global__ void k_deg(const int* __restrict__ dst, const float* __restrict__ w,
                      unsigned long long* __restrict__ packed) {
    int e = blockIdx.x * blockDim.x + threadIdx.x;
    if (e < N_EDGES) {
        int d = dst[e];
        unsigned long long q = (1ULL << 40)
                             + (unsigned long long)__float2uint_rn(w[e] * WSCALE);
        atomicAdd(&packed[d], q);
    }
}

__global__ void k_dinv(const unsigned long long* __restrict__ packed,
                       float* __restrict__ dinv, int* __restrict__ counts) {
    int i = blockIdx.x * blockDim.x + threadIdx.x;
    if (i < N_NODES) {
        unsigned long long p = packed[i];
        counts[i] = (int)(p >> 40);
        float wsum = (float)(p & 0xFFFFFFFFFFULL) * (1.0f / WSCALE);
        dinv[i] = rsqrtf(1.0f + wsum);   // self-loop contributes 1
    }
}

// ---------------------------------------------------------------- two-level scan
__global__ __launch_bounds__(256) void k_scan_blk(const int* __restrict__ counts,
                                                  int* __restrict__ incl,
                                                  int* __restrict__ bsum) {
    __shared__ int sm[256];
    int tid = threadIdx.x;
    int i = blockIdx.x * 256 + tid;
    int v = (i < N_NODES) ? counts[i] : 0;
    sm[tid] = v;
    __syncthreads();
    for (int off = 1; off < 256; off <<= 1) {
        int t = (tid >= off) ? sm[tid - off] : 0;
        __syncthreads();
        sm[tid] += t;
        __syncthreads();
    }
    if (i < N_NODES) incl[i] = sm[tid];
    if (tid == 255) bsum[blockIdx.x] = sm[255];
}

__global__ __launch_bounds__(256) void k_scan_top(const int* __restrict__ bsum,
                                                  int* __restrict__ boff) {
    __shared__ int sm[256];
    int tid = threadIdx.x;
    int v = (tid < N_CHUNKBLKS) ? bsum[tid] : 0;
    sm[tid] = v;
    __syncthreads();
    for (int off = 1; off < 256; off <<= 1) {
        int t = (tid >= off) ? sm[tid - off] : 0;
        __syncthreads();
        sm[tid] += t;
        __syncthreads();
    }
    if (tid < N_CHUNKBLKS) boff[tid] = sm[tid] - v;   // exclusive
}

__global__ __launch_bounds__(256) void k_scan_add(const int* __restrict__ incl,
                                                  const int* __restrict__ boff,
                                                  const int* __restrict__ counts,
                                                  int* __restrict__ row_ptr,
                                                  int* __restrict__ cursor) {
    int i = blockIdx.x * 256 + threadIdx.x;
    if (i < N_NODES) {
        int ip = incl[i] + boff[blockIdx.x];
        row_ptr[i + 1] = ip;
        cursor[i] = ip - counts[i];
        if (i == 0) row_ptr[0] = 0;
    }
}

// ---------------------------------------------------------------- CSR fill (packed records)
__global__ void k_fill(const int* __restrict__ src, const int* __restrict__ dst,
                       const float* __restrict__ w, const float* __restrict__ dinv,
                       int* __restrict__ cursor, int2* __restrict__ recs) {
    int e = blockIdx.x * blockDim.x + threadIdx.x;
    if (e < N_EDGES) {
        int s = src[e], d = dst[e];
        int pos = atomicAdd(&cursor[d], 1);
        float nr = dinv[s] * w[e] * dinv[d];
        recs[pos] = make_int2(s, __float_as_int(nr));
    }
}

// ---------------------------------------------------------------- GEMM: out[N,128] = [in1|in2] @ W
// BM=128 rows/block, 256 threads, each thread: 4 rows x 16 cols. BK=32.
// d1, d2 must be multiples of 32 (128/0 and 128/32 here).
#define GBM 128
#define GBK 32
__global__ __launch_bounds__(256) void k_gemm(
    const float* __restrict__ in1, int d1,
    const float* __restrict__ in2, int d2,
    const float* __restrict__ W,      // [(d1+d2) x 128]
    float* __restrict__ out)          // [N x 128]
{
    __shared__ float xs[GBM][GBK + 1];   // 128x33
    __shared__ float ws[GBK][128];       // 32x128
    int tid = threadIdx.x;
    int cx = tid & 7;          // cols cx*16 .. cx*16+15
    int ry = tid >> 3;         // rows ry*4 .. ry*4+3
    int row0 = blockIdx.x * GBM;
    float acc[4][16];
#pragma unroll
    for (int i = 0; i < 4; ++i)
#pragma unroll
        for (int j = 0; j < 16; ++j) acc[i][j] = 0.0f;
    int KD = d1 + d2;
    for (int kt = 0; kt < KD; kt += GBK) {
        const float* srcp; int sd, scol;
        if (kt < d1) { srcp = in1; sd = d1; scol = kt; }
        else         { srcp = in2; sd = d2; scol = kt - d1; }
        // stage xs: 128 rows x 32 k, as float4 (1024 vec4, 4/thread)
#pragma unroll
        for (int i = 0; i < 4; ++i) {
            int vid = tid + i * 256;
            int rr = vid >> 3;
            int kc = (vid & 7) * 4;
            int r = row0 + rr;
            float4 val = make_float4(0.f, 0.f, 0.f, 0.f);
            if (r < N_NODES)
                val = *(const float4*)(srcp + (size_t)r * sd + scol + kc);
            xs[rr][kc + 0] = val.x;
            xs[rr][kc + 1] = val.y;
            xs[rr][kc + 2] = val.z;
            xs[rr][kc + 3] = val.w;
        }
        // stage ws: 32 k x 128 cols (1024 vec4, 4/thread)
#pragma unroll
        for (int i = 0; i < 4; ++i) {
            int vid = tid + i * 256;
            int kk = vid >> 5;
            int c = (vid & 31) * 4;
            *(float4*)&ws[kk][c] = *(const float4*)(W + (size_t)(kt + kk) * 128 + c);
        }
        __syncthreads();
#pragma unroll
        for (int kk = 0; kk < GBK; ++kk) {
            float xv[4];
#pragma unroll
            for (int i = 0; i < 4; ++i) xv[i] = xs[ry * 4 + i][kk];
            float wv[16];
            *(float4*)&wv[0]  = *(float4*)&ws[kk][cx * 16 + 0];
            *(float4*)&wv[4]  = *(float4*)&ws[kk][cx * 16 + 4];
            *(float4*)&wv[8]  = *(float4*)&ws[kk][cx * 16 + 8];
            *(float4*)&wv[12] = *(float4*)&ws[kk][cx * 16 + 12];
#pragma unroll
            for (int i = 0; i < 4; ++i)
#pragma unroll
                for (int j = 0; j < 16; ++j)
                    acc[i][j] += xv[i] * wv[j];
        }
        __syncthreads();
    }
#pragma unroll
    for (int i = 0; i < 4; ++i) {
        int r = row0 + ry * 4 + i;
        if (r < N_NODES) {
            float4* o = (float4*)(out + (size_t)r * 128 + cx * 16);
            o[0] = *(float4*)&acc[i][0];
            o[1] = *(float4*)&acc[i][4];
            o[2] = *(float4*)&acc[i][8];
            o[3] = *(float4*)&acc[i][12];
        }
    }
}

// ---------------------------------------------------------------- aggregation (CSR gather)
__global__ __launch_bounds__(256) void k_agg(
    const float* __restrict__ t, const float* __restrict__ dinv,
    const int* __restrict__ row_ptr, const int2* __restrict__ recs,
    const float* __restrict__ bias,
    float* __restrict__ out, int relu_flag,
    const float* __restrict__ attr, const float* __restrict__ q,
    float* __restrict__ scores, int score_flag)
{
    int lane = threadIdx.x & 31;
    int node = blockIdx.x * 8 + (threadIdx.x >> 5);
    if (node >= N_NODES) return;
    const float4* t4 = (const float4*)t;
    float di = dinv[node];
    float sw = di * di;
    float4 v = t4[node * 32 + lane];
    float4 acc;
    acc.x = v.x * sw; acc.y = v.y * sw; acc.z = v.z * sw; acc.w = v.w * sw;
    int e0 = row_ptr[node], e1 = row_ptr[node + 1];
    for (int e = e0; e < e1; ++e) {
        int2 rec = recs[e];
        int s = rec.x;
        float wn = __int_as_float(rec.y);
        float4 u = t4[s * 32 + lane];
        acc.x += wn * u.x; acc.y += wn * u.y; acc.z += wn * u.z; acc.w += wn * u.w;
    }
    const float4* b4 = (const float4*)bias;
    float4 bb = b4[lane];
    acc.x += bb.x; acc.y += bb.y; acc.z += bb.z; acc.w += bb.w;
    if (relu_flag) {
        acc.x = fmaxf(acc.x, 0.0f); acc.y = fmaxf(acc.y, 0.0f);
        acc.z = fmaxf(acc.z, 0.0f); acc.w = fmaxf(acc.w, 0.0f);
    }
    ((float4*)out)[node * 32 + lane] = acc;
    if (score_flag) {
        const float4* q4 = (const float4*)q;
        float4 qq = q4[lane];
        float s = acc.x * qq.x + acc.y * qq.y + acc.z * qq.z + acc.w * qq.w;
        if (lane < 8) {
            const float4* at4 = (const float4*)attr;
            float4 b = at4[node * 8 + lane];
            float4 q2 = q4[32 + lane];
            s += b.x * q2.x + b.y * q2.y + b.z * q2.z + b.w * q2.w;
        }
        for (int off = 16; off; off >>= 1) s += __shfl_xor(s, off, 32);
        if (lane == 0) scores[node] = s;
    }
}

// ---------------------------------------------------------------- q = hidden_state @ Wattn  [160]
__global__ void k_q(const float* __restrict__ hs, const float* __restrict__ Wattn,
                    float* __restrict__ q) {
    int j = threadIdx.x;
    if (j >= D_CAT) return;
    int k0 = blockIdx.x * (D_H / 8);       // grid 8
    float acc = 0.0f;
    for (int k = k0; k < k0 + D_H / 8; k++) acc += hs[k] * Wattn[k * D_CAT + j];
    atomicAdd(&q[j], acc);
}

// ---------------------------------------------------------------- column sums for mean pool
__global__ void k_colsum(const float* __restrict__ h2, const float* __restrict__ attr,
                         float* __restrict__ colsum) {
    int j = threadIdx.x;
    int per = (N_NODES + gridDim.x - 1) / gridDim.x;
    int r0 = blockIdx.x * per;
    int r1 = min(N_NODES, r0 + per);
    float acc = 0.0f;
    if (j < D_OUT) {
        for (int i = r0; i < r1; i++) acc += h2[i * D_OUT + j];
        atomicAdd(&colsum[j], acc);
    } else if (j < D_CAT) {
        int jj = j - D_OUT;
        for (int i = r0; i < r1; i++) acc += attr[i * D_ATTR + jj];
        atomicAdd(&colsum[j], acc);
    }
}

// ---------------------------------------------------------------- top-k stage 1
__global__ __launch_bounds__(256) void k_top1(const float* __restrict__ scores,
                                              float* __restrict__ cand_s,
                                              int* __restrict__ cand_i) {
    __shared__ float ss[256];
    __shared__ int si[256];
    __shared__ float rs[256];
    __shared__ int ri[256];
    int tid = threadIdx.x;
    int i = blockIdx.x * 256 + tid;
    ss[tid] = (i < N_NODES) ? scores[i] : -INFINITY;
    si[tid] = i;
    __syncthreads();
    for (int it = 0; it < K_TOP; ++it) {
        rs[tid] = ss[tid]; ri[tid] = si[tid];
        __syncthreads();
        for (int off = 128; off; off >>= 1) {
            if (tid < off) {
                float s2 = rs[tid + off]; int i2 = ri[tid + off];
                if (s2 > rs[tid] || (s2 == rs[tid] && i2 < ri[tid])) { rs[tid] = s2; ri[tid] = i2; }
            }
            __syncthreads();
        }
        if (tid == 0) {
            cand_s[blockIdx.x * K_TOP + it] = rs[0];
            cand_i[blockIdx.x * K_TOP + it] = ri[0];
        }
        __syncthreads();
        if (si[tid] == ri[0]) ss[tid] = -INFINITY;
        __syncthreads();
    }
}

// ---------------------------------------------------------------- top-k stage 2: register-resident
__global__ __launch_bounds__(256) void k_top2(const float* __restrict__ cand_s,
                                              const int* __restrict__ cand_i,
                                              int* __restrict__ topidx) {
    float s[CSLOTS]; int ix[CSLOTS];
    int tid = threadIdx.x;
    int lane = tid & 63;
    int wave = tid >> 6;
#pragma unroll
    for (int j = 0; j < CSLOTS; ++j) {
        int c = tid + j * 256;
        s[j]  = (c < N_CAND) ? cand_s[c] : -INFINITY;
        ix[j] = (c < N_CAND) ? cand_i[c] : 0x7fffffff;
    }
    __shared__ float wsum_s[4];
    __shared__ int   wsum_i[4];
    __shared__ int   win_i;
    for (int it = 0; it < K_TOP; ++it) {
        float bs = -INFINITY; int bi = 0x7fffffff;
#pragma unroll
        for (int j = 0; j < CSLOTS; ++j) {
            if (s[j] > bs || (s[j] == bs && ix[j] < bi)) { bs = s[j]; bi = ix[j]; }
        }
#pragma unroll
        for (int off = 32; off; off >>= 1) {
            float s2 = __shfl_xor(bs, off, 64);
            int   i2 = __shfl_xor(bi, off, 64);
            if (s2 > bs || (s2 == bs && i2 < bi)) { bs = s2; bi = i2; }
        }
        if (lane == 0) { wsum_s[wave] = bs; wsum_i[wave] = bi; }
        __syncthreads();
        if (tid == 0) {
            float ws0 = wsum_s[0]; int wi0 = wsum_i[0];
#pragma unroll
            for (int w = 1; w < 4; ++w) {
                float s2 = wsum_s[w]; int i2 = wsum_i[w];
                if (s2 > ws0 || (s2 == ws0 && i2 < wi0)) { ws0 = s2; wi0 = i2; }
            }
            win_i = wi0;
            topidx[it] = wi0;
        }
        __syncthreads();
        int w = win_i;
#pragma unroll
        for (int j = 0; j < CSLOTS; ++j)
            if (ix[j] == w) s[j] = -INFINITY;
        __syncthreads();
    }
}

// ---------------------------------------------------------------- emb GEMV + top-node gather
__global__ __launch_bounds__(256) void k_emb_gather(
    const float* __restrict__ colsum, const float* __restrict__ Wmap,
    const float* __restrict__ bmap, const int* __restrict__ topidx,
    const float* __restrict__ h2, const float* __restrict__ attr,
    float* __restrict__ out)
{
    int tid = threadIdx.x;
    __shared__ float cs[D_CAT];
    if (tid < D_CAT) cs[tid] = colsum[tid];
    __syncthreads();
    float acc = 0.0f;
#pragma unroll 8
    for (int k = 0; k < D_CAT; ++k) acc += cs[k] * Wmap[k * D_EMB + tid];
    out[tid] = acc * (1.0f / N_NODES) + bmap[tid];
    __shared__ int ti[K_TOP];
    if (tid < K_TOP) ti[tid] = topidx[tid];
    __syncthreads();
    for (int idx = tid; idx < K_TOP * D_CAT; idx += 256) {
        int kk = idx / D_CAT;
        int d = idx % D_CAT;
        int node = ti[kk];
        out[D_EMB + idx] = (d < D_OUT) ? h2[node * D_OUT + d]
                                       : attr[node * D_ATTR + (d - D_OUT)];
    }
}

// ================================================================ host
extern "C" void kernel_launch(void* const* d_in, const int* in_sizes, int n_in,
                              void* d_out, int out_size, void* d_ws, size_t ws_size,
                              hipStream_t stream) {
    const float* x      = (const float*)d_in[0];
    const float* attr   = (const float*)d_in[1];
    const float* ew     = (const float*)d_in[2];
    const float* hs     = (const float*)d_in[3];
    const int*   ei     = (const int*)d_in[4];
    const float* W1     = (const float*)d_in[5];
    const float* b1     = (const float*)d_in[6];
    const float* W2     = (const float*)d_in[7];
    const float* b2     = (const float*)d_in[8];
    const float* Wmap   = (const float*)d_in[9];
    const float* bmap   = (const float*)d_in[10];
    const float* Wattn  = (const float*)d_in[11];
    float* out = (float*)d_out;
    const int* e_src = ei;
    const int* e_dst = ei + N_EDGES;

    size_t off = 0;
    auto alloc = [&](size_t bytes) {
        void* p = (char*)d_ws + off;
        off += (bytes + 255) / 256 * 256;
        return p;
    };
    unsigned long long* packed = (unsigned long long*)alloc((size_t)N_NODES * 8);
    float* dinv   = (float*)alloc((size_t)N_NODES * 4);
    int*   counts = (int*)  alloc((size_t)N_NODES * 4);
    int*   rowp   = (int*)  alloc((size_t)(N_NODES + 1) * 4);
    int*   cursor = (int*)  alloc((size_t)N_NODES * 4);
    int2*  recs   = (int2*) alloc((size_t)N_EDGES * 8);
    float* bufA   = (float*)alloc((size_t)N_NODES * 128 * 4);
    float* bufB   = (float*)alloc((size_t)N_NODES * 128 * 4);
    float* scores = (float*)alloc((size_t)N_NODES * 4);
    float* q      = (float*)alloc(D_CAT * 4);
    float* colsum = (float*)alloc(D_CAT * 4);
    float* cand_s = (float*)alloc((size_t)N_CAND * 4);
    int*   cand_i = (int*)  alloc((size_t)N_CAND * 4);
    int*   incl   = (int*)  alloc((size_t)N_NODES * 4);
    int*   bsum   = (int*)  alloc((size_t)N_CHUNKBLKS * 4);
    int*   boff   = (int*)  alloc((size_t)N_CHUNKBLKS * 4);
    int*   topidx = (int*)  alloc((size_t)K_TOP * 4);

    int nblk = (N_NODES + 255) / 256;     // 196
    int eblk = (N_EDGES + 255) / 256;     // 2344

    hipLaunchKernelGGL(k_init, dim3(nblk), dim3(256), 0, stream, packed, colsum, q);
    hipLaunchKernelGGL(k_deg, dim3(eblk), dim3(256), 0, stream, e_dst, ew, packed);
    hipLaunchKernelGGL(k_dinv, dim3(nblk), dim3(256), 0, stream, packed, dinv, counts);
    hipLaunchKernelGGL(k_scan_blk, dim3(nblk), dim3(256), 0, stream, counts, incl, bsum);
    hipLaunchKernelGGL(k_scan_top, dim3(1), dim3(256), 0, stream, bsum, boff);
    hipLaunchKernelGGL(k_scan_add, dim3(nblk), dim3(256), 0, stream, incl, boff, counts,
                       rowp, cursor);
    hipLaunchKernelGGL(k_fill, dim3(eblk), dim3(256), 0, stream, e_src, e_dst, ew, dinv,
                       cursor, recs);
    hipLaunchKernelGGL(k_q, dim3(8), dim3(192), 0, stream, hs, Wattn, q);
    // conv1
    hipLaunchKernelGGL(k_gemm, dim3((N_NODES + GBM - 1) / GBM), dim3(256), 0, stream,
                       x, D_IN, x, 0, W1, bufA);
    hipLaunchKernelGGL(k_agg, dim3(N_NODES / 8), dim3(256), 0, stream,
                       bufA, dinv, rowp, recs, b1, bufB, 1,
                       (const float*)nullptr, (const float*)nullptr, (float*)nullptr, 0);
    // conv2 + fused scores
    hipLaunchKernelGGL(k_gemm, dim3((N_NODES + GBM - 1) / GBM), dim3(256), 0, stream,
                       bufB, D_MID, attr, D_ATTR, W2, bufA);
    hipLaunchKernelGGL(k_agg, dim3(N_NODES / 8), dim3(256), 0, stream,
                       bufA, dinv, rowp, recs, b2, bufB, 0,
                       attr, q, scores, 1);
    // epilogue
    hipLaunchKernelGGL(k_colsum, dim3(256), dim3(192), 0, stream, bufB, attr, colsum);
    hipLaunchKernelGGL(k_top1, dim3(N_CHUNKBLKS), dim3(256), 0, stream,
                       scores, cand_s, cand_i);
    hipLaunchKernelGGL(k_top2, dim3(1), dim3(256), 0, stream, cand_s, cand_i, topidx);
    hipLaunchKernelGGL(k_emb_gather, dim3(1), dim3(256), 0, stream,
                       colsum, Wmap, bmap, topidx, bufB, attr, out);
}